// Round 7
// baseline (91.589 us; speedup 1.0000x reference)
//
#include <hip/hip_runtime.h>

namespace {

constexpr int NS = 256;      // samples
constexpr int MP = 128;      // patches
constexpr int TSTEPS = 200;  // timesteps
constexpr int BLK = 512;     // 8 waves -> 2 waves/SIMD

typedef float f2 __attribute__((ext_vector_type(2)));

__device__ __forceinline__ float4 ldg4(const float* p) {
  return *reinterpret_cast<const float4*>(p);
}
__device__ __forceinline__ float clamp01(float v) {
  return fminf(fmaxf(v, 0.0f), 1.0f);
}
// LDS-visibility barrier that does NOT drain vmcnt (stores stay in flight).
__device__ __forceinline__ void step_barrier() {
  asm volatile("s_waitcnt lgkmcnt(0)" ::: "memory");
  __builtin_amdgcn_s_barrier();
  asm volatile("" ::: "memory");
}
// guaranteed packed f32 FMA (full-rate on CDNA3/4)
__device__ __forceinline__ f2 pk_fma(f2 a, f2 b, f2 c) {
  f2 d;
  asm("v_pk_fma_f32 %0, %1, %2, %3" : "=v"(d) : "v"(a), "v"(b), "v"(c));
  return d;
}
// x + dpp_perm(y): CTRL=0xB1 quad_perm[1,0,3,2] (xor1), 0x4E quad_perm[2,3,0,1]
// (xor2), 0x124/0x128 row_ror:4/8.
template <int CTRL>
__device__ __forceinline__ float dpp_add(float x, float y) {
  int yi = __builtin_amdgcn_update_dpp(0, __float_as_int(y), CTRL, 0xF, 0xF, true);
  return x + __int_as_float(yi);
}
// Swizzled float4 index into Q staging (row-major 32 float4/row, col-quad XOR).
__device__ __forceinline__ int qidx(int row, int c4) {
  return (row << 5) + (c4 ^ ((row >> 3) & 7));
}

__global__ __launch_bounds__(BLK, 2)
void sir_meta_kernel(const float* __restrict__ Rg,
                     const float* __restrict__ Tg,
                     const float* __restrict__ rho0g,
                     const float* __restrict__ betag,
                     float* __restrict__ outg)
{
  __shared__ __align__(16) float rs[MP];        // 1/rowsum
  __shared__ __align__(16) float sbin[MP];      // sqrt(beta/neff)
  __shared__ __align__(16) float scr[BLK];
  __shared__ __align__(16) float xb[2][MP];     // x, Gray-coded float4 blocks
  __shared__ __align__(16) float qlds[MP * MP]; // Q = R*diag(sbin), swizzled
  __shared__ __align__(16) float glds[MP * 132];// G, stride 132 floats

  const int tid = threadIdx.x;
  const int n = blockIdx.x;
  const float* __restrict__ Rn = Rg + (size_t)n * MP * MP;

  // ---- S1: row sums -> rs = 1/rowsum ----
  {
    const int wave = tid >> 6;
    const int lane = tid & 63;
    const int half = lane >> 5;
    const int l32 = lane & 31;
    for (int it = 0; it < 8; ++it) {
      const int row = wave * 16 + it * 2 + half;
      float4 v = ldg4(Rn + row * MP + l32 * 4);
      float s = (v.x + v.y) + (v.z + v.w);
      s += __shfl_xor(s, 1);
      s += __shfl_xor(s, 2);
      s += __shfl_xor(s, 4);
      s += __shfl_xor(s, 8);
      s += __shfl_xor(s, 16);
      if (l32 == 0) rs[row] = 1.0f / s;
    }
  }
  __syncthreads();

  // ---- S2: neff[c] = sum_i Rraw[i][c]*rs[i] -> sbin = sqrt(beta/neff) ----
  {
    const int c = tid & 127;
    const int h = tid >> 7;
    float a = 0.0f;
    #pragma unroll 8
    for (int i = 0; i < 32; ++i) {
      const int ig = h * 32 + i;
      a = fmaf(Rn[ig * MP + c], rs[ig], a);
    }
    scr[tid] = a;
  }
  __syncthreads();
  if (tid < 128)
    sbin[tid] = sqrtf(betag[n] /
        (((scr[tid] + scr[tid + 128]) + (scr[tid + 256] + scr[tid + 384]))));
  __syncthreads();

  // ---- S3a: stage Q = Rraw * diag(sbin) into LDS, swizzled ----
  {
    float4* q4 = reinterpret_cast<float4*>(qlds);
    #pragma unroll
    for (int u = 0; u < 8; ++u) {
      const int fi = u * BLK + tid;
      const int r = fi >> 5, c4 = fi & 31;
      float4 rv = ldg4(Rn + fi * 4);
      float4 sv = *reinterpret_cast<const float4*>(&sbin[c4 * 4]);
      q4[qidx(r, c4)] =
          make_float4(rv.x * sv.x, rv.y * sv.y, rv.z * sv.z, rv.w * sv.w);
    }
  }
  __syncthreads();

  // ---- S3b: 4-wave 8x8-tile GEMM  G = diag(rs) * Q Q^T * diag(rs) ----
  // (4 waves x 64 lanes x 64 accs = 16384 = full G; waves 4-7 skip to sync)
  if (tid < 256) {
    const int wv4 = tid >> 6;
    const int g4i = (tid >> 4) & 3;
    const int k4 = tid & 15;
    const int rb = wv4 * 32 + g4i * 8;
    const int cb = k4 * 8;
    float acc[64];
    #pragma unroll
    for (int i = 0; i < 64; ++i) acc[i] = 0.0f;
    {
      const float4* q4 = reinterpret_cast<const float4*>(qlds);
      for (int kk = 0; kk < 32; ++kk) {
        float4 qa[8], qb[8];
        #pragma unroll
        for (int r = 0; r < 8; ++r) qa[r] = q4[qidx(rb + r, kk)];
        #pragma unroll
        for (int c = 0; c < 8; ++c) qb[c] = q4[qidx(cb + c, kk)];
        #pragma unroll
        for (int r = 0; r < 8; ++r) {
          #pragma unroll
          for (int c = 0; c < 8; ++c) {
            float a = acc[r * 8 + c];
            a = fmaf(qa[r].x, qb[c].x, a);
            a = fmaf(qa[r].y, qb[c].y, a);
            a = fmaf(qa[r].z, qb[c].z, a);
            a = fmaf(qa[r].w, qb[c].w, a);
            acc[r * 8 + c] = a;
          }
        }
      }
    }
    // scale + write to glds (row stride 132 floats = 33 float4)
    {
      float rsc[8];
      #pragma unroll
      for (int c = 0; c < 8; ++c) rsc[c] = rs[cb + c];
      float4* g4p = reinterpret_cast<float4*>(glds);
      #pragma unroll
      for (int r = 0; r < 8; ++r) {
        const float rr = rs[rb + r];
        float4 lo = make_float4(acc[r*8+0] * rr * rsc[0], acc[r*8+1] * rr * rsc[1],
                                acc[r*8+2] * rr * rsc[2], acc[r*8+3] * rr * rsc[3]);
        float4 hi = make_float4(acc[r*8+4] * rr * rsc[4], acc[r*8+5] * rr * rsc[5],
                                acc[r*8+6] * rr * rsc[6], acc[r*8+7] * rr * rsc[7]);
        g4p[(rb + r) * 33 + 2 * k4]     = lo;
        g4p[(rb + r) * 33 + 2 * k4 + 1] = hi;
      }
    }
  }
  __syncthreads();

  // ---- redistribute: 8-wave loop tiling. Lane owns 4 rows x 8 cols. ----
  const int wv = tid >> 6;
  const int g = (tid >> 4) & 3;
  const int k = tid & 15;
  const int rbase = wv * 16 + g * 4;

  f2 ac[4][4];
  {
    const float4* g4p = reinterpret_cast<const float4*>(glds);
    #pragma unroll
    for (int r = 0; r < 4; ++r) {
      float4 lo = g4p[(rbase + r) * 33 + 2 * k];
      float4 hi = g4p[(rbase + r) * 33 + 2 * k + 1];
      ac[r][0] = f2{lo.x, lo.y}; ac[r][1] = f2{lo.z, lo.w};
      ac[r][2] = f2{hi.x, hi.y}; ac[r][3] = f2{hi.z, hi.w};
    }
  }

  // ---- S4: state init. Lane updates row j = rbase + (k&3). ----
  const int j = rbase + (k & 3);
  const bool writer = (k < 4);
  const int jb = j >> 2;
  const int wslot = ((jb ^ (jb >> 1)) << 2) | (j & 3);  // Gray-coded float slot
  const int bA = (2 * k) ^ k;        // gray(2k)   : float4 block position
  const int bB = (2 * k + 1) ^ k;    // gray(2k+1)
  const float* Tn = Tg + n * 9;
  const float T00 = Tn[0], T01 = Tn[1], T02 = Tn[2];
  const float T10 = Tn[3], T11 = Tn[4], T12 = Tn[5];
  const float T20 = Tn[6], T21 = Tn[7], T22 = Tn[8];
  const float* rp0 = rho0g + ((size_t)n * MP + j) * 3;
  float r0 = rp0[0], r1 = rp0[1], r2 = rp0[2];
  if (writer) xb[0][wslot] = r0;
  __syncthreads();

  float4* outp = reinterpret_cast<float4*>(outg) + (size_t)n * TSTEPS * MP + j;

  for (int s = 0; s < TSTEPS; ++s) {
    // emit pre-update state (fire-and-forget)
    const float S = 1.0f - ((r0 + r1) + r2);
    if (writer) *outp = make_float4(S, r0, r1, r2);
    outp += MP;

    // x: 2 Gray-spread b128 reads (2-way banks = free)
    const float4* xc4 = reinterpret_cast<const float4*>(xb[s & 1]);
    const float4 xA = xc4[bA];
    const float4 xB = xc4[bB];
    const f2 x0p = f2{xA.x, xA.y}, x1p = f2{xA.z, xA.w};
    const f2 x2p = f2{xB.x, xB.y}, x3p = f2{xB.z, xB.w};

    // packed 4x8 tile matvec
    float p0, p1, p2, p3;
    {
      f2 s0 = ac[0][0] * x0p;
      s0 = pk_fma(ac[0][1], x1p, s0);
      s0 = pk_fma(ac[0][2], x2p, s0);
      s0 = pk_fma(ac[0][3], x3p, s0);
      p0 = s0.x + s0.y;
      f2 s1 = ac[1][0] * x0p;
      s1 = pk_fma(ac[1][1], x1p, s1);
      s1 = pk_fma(ac[1][2], x2p, s1);
      s1 = pk_fma(ac[1][3], x3p, s1);
      p1 = s1.x + s1.y;
      f2 s2 = ac[2][0] * x0p;
      s2 = pk_fma(ac[2][1], x1p, s2);
      s2 = pk_fma(ac[2][2], x2p, s2);
      s2 = pk_fma(ac[2][3], x3p, s2);
      p2 = s2.x + s2.y;
      f2 s3 = ac[3][0] * x0p;
      s3 = pk_fma(ac[3][1], x1p, s3);
      s3 = pk_fma(ac[3][2], x2p, s3);
      s3 = pk_fma(ac[3][3], x3p, s3);
      p3 = s3.x + s3.y;
    }

    // folded reduce: merge rows while reducing across the 16-lane group.
    // After it, lane k holds row (k&3) fully reduced.
    float t0 = (k & 1) ? p1 : p0;
    float o0 = (k & 1) ? p0 : p1;
    t0 = dpp_add<0xB1>(t0, o0);        // xor1
    float t1 = (k & 1) ? p3 : p2;
    float o1 = (k & 1) ? p2 : p3;
    t1 = dpp_add<0xB1>(t1, o1);        // xor1
    float u = (k & 2) ? t1 : t0;
    float oo = (k & 2) ? t0 : t1;
    u = dpp_add<0x4E>(u, oo);          // xor2
    u = dpp_add<0x124>(u, u);          // ror4
    u = dpp_add<0x128>(u, u);          // ror8

    // n0 (feeds x) before barrier; n1/n2 + commit in the post-barrier shadow
    const float ni = S * u;
    const float o0s = r0, o1s = r1, o2s = r2;
    const float n0 = clamp01(fmaf(o0s, T00, fmaf(o1s, T10, fmaf(o2s, T20, ni))));
    if (writer) xb[(s & 1) ^ 1][wslot] = n0;
    step_barrier();
    r0 = n0;
    r1 = clamp01(fmaf(o0s, T01, fmaf(o1s, T11, o2s * T21)));
    r2 = clamp01(fmaf(o0s, T02, fmaf(o1s, T12, o2s * T22)));
  }
}

} // namespace

extern "C" void kernel_launch(void* const* d_in, const int* in_sizes, int n_in,
                              void* d_out, int out_size, void* d_ws, size_t ws_size,
                              hipStream_t stream)
{
  const float* Rg    = (const float*)d_in[0];
  const float* Tg    = (const float*)d_in[1];
  const float* rho0g = (const float*)d_in[2];
  const float* betag = (const float*)d_in[3];
  float* outg = (float*)d_out;
  sir_meta_kernel<<<NS, BLK, 0, stream>>>(Rg, Tg, rho0g, betag, outg);
}